// Round 2
// baseline (293.950 us; speedup 1.0000x reference)
//
#include <hip/hip_runtime.h>

#define DIN 48
#define DOUT 16
#define DC 32  // combined output dims: [mu(16) | logstd(16)]

// ======================= CSR (gather) path =======================

__global__ void k_init_i(int* __restrict__ cnt, int* __restrict__ fill, int n) {
    int i = blockIdx.x * blockDim.x + threadIdx.x;
    if (i < n) { cnt[i] = 0; fill[i] = 0; }
}

__global__ void k_hist(const int* __restrict__ dst, int* __restrict__ cnt, int e_cnt) {
    int e = blockIdx.x * blockDim.x + threadIdx.x;
    if (e < e_cnt) atomicAdd(&cnt[dst[e]], 1);
}

// per-block inclusive scan -> exclusive offsets + block sums
__global__ void k_scanA(const int* __restrict__ cnt, int* __restrict__ offs,
                        int* __restrict__ bsum, int n) {
    __shared__ int sd[256];
    int t = threadIdx.x;
    int i = blockIdx.x * 256 + t;
    int v = (i < n) ? cnt[i] : 0;
    sd[t] = v;
    __syncthreads();
#pragma unroll
    for (int off = 1; off < 256; off <<= 1) {
        int x = (t >= off) ? sd[t - off] : 0;
        __syncthreads();
        sd[t] += x;
        __syncthreads();
    }
    if (i < n) offs[i] = sd[t] - v;          // exclusive
    if (t == 255) bsum[blockIdx.x] = sd[t];  // block total
}

// single block scans <=512 block sums in place (exclusive)
__global__ void k_scanB(int* __restrict__ bsum, int nb) {
    __shared__ int sd[512];
    int t = threadIdx.x;
    int v = (t < nb) ? bsum[t] : 0;
    sd[t] = v;
    __syncthreads();
#pragma unroll
    for (int off = 1; off < 512; off <<= 1) {
        int x = (t >= off) ? sd[t - off] : 0;
        __syncthreads();
        sd[t] += x;
        __syncthreads();
    }
    if (t < nb) bsum[t] = sd[t] - v;  // exclusive
}

__global__ void k_scanC(int* __restrict__ offs, const int* __restrict__ bsum, int n) {
    int i = blockIdx.x * blockDim.x + threadIdx.x;
    if (i < n) offs[i] += bsum[i >> 8];
}

__global__ void k_reorder(const int* __restrict__ src, const int* __restrict__ dst,
                          const int* __restrict__ offs, int* __restrict__ fill,
                          int* __restrict__ esrc, int e_cnt) {
    int e = blockIdx.x * blockDim.x + threadIdx.x;
    if (e >= e_cnt) return;
    int d = dst[e];
    int pos = offs[d] + atomicAdd(&fill[d], 1);
    esrc[pos] = src[e];
}

// proj = x @ [Wmu|Wls]; dinv = rsqrt(1+cnt); out = bias + dinv^2*proj (self-loop)
__global__ void k_proj2(const float* __restrict__ x,
                        const float* __restrict__ Wmu, const float* __restrict__ bmu,
                        const float* __restrict__ Wls, const float* __restrict__ bls,
                        const int* __restrict__ cnt, float* __restrict__ dinv,
                        float* __restrict__ proj, float* __restrict__ out, int n) {
    __shared__ float Ws[DIN * DC];
    __shared__ float bs[DC];
    int t = threadIdx.x;
    for (int idx = t; idx < DIN * DC; idx += blockDim.x) {
        int k = idx >> 5, j = idx & 31;
        Ws[idx] = (j < DOUT) ? Wmu[k * DOUT + j] : Wls[k * DOUT + (j - DOUT)];
    }
    if (t < DC) bs[t] = (t < DOUT) ? bmu[t] : bls[t - DOUT];
    __syncthreads();

    int i = blockIdx.x * blockDim.x + t;
    if (i >= n) return;

    float xr[DIN];
    const float4* xp = reinterpret_cast<const float4*>(x + (size_t)i * DIN);
#pragma unroll
    for (int q = 0; q < DIN / 4; ++q) {
        float4 v = xp[q];
        xr[4 * q + 0] = v.x; xr[4 * q + 1] = v.y;
        xr[4 * q + 2] = v.z; xr[4 * q + 3] = v.w;
    }

    float acc[DC];
#pragma unroll
    for (int j = 0; j < DC; ++j) acc[j] = 0.0f;
#pragma unroll 4
    for (int k = 0; k < DIN; ++k) {
        float xv = xr[k];
#pragma unroll
        for (int j = 0; j < DC; ++j) acc[j] += xv * Ws[k * DC + j];
    }

    float dv = rsqrtf(1.0f + (float)cnt[i]);
    dinv[i] = dv;
    float d2 = dv * dv;

    float4* pp = reinterpret_cast<float4*>(proj + (size_t)i * DC);
#pragma unroll
    for (int q = 0; q < DC / 4; ++q) {
        float4 v;
        v.x = acc[4 * q + 0]; v.y = acc[4 * q + 1];
        v.z = acc[4 * q + 2]; v.w = acc[4 * q + 3];
        pp[q] = v;
    }

    float* omu = out + (size_t)i * DOUT;
    float* ols = out + (size_t)n * DOUT + (size_t)i * DOUT;
#pragma unroll
    for (int j = 0; j < DOUT; ++j) omu[j] = bs[j] + d2 * acc[j];
#pragma unroll
    for (int j = 0; j < DOUT; ++j) ols[j] = bs[DOUT + j] + d2 * acc[DOUT + j];
}

// one 32-lane group per dst node; lane j owns combined-dim j. No atomics.
__global__ void k_agg(const int* __restrict__ esrc, const int* __restrict__ offs,
                      const float* __restrict__ dinv, const float* __restrict__ proj,
                      float* __restrict__ out, int n, int e_cnt) {
    int t = threadIdx.x;
    int g = t >> 5, j = t & 31;
    int d = blockIdx.x * 8 + g;
    if (d >= n) return;
    int start = offs[d];
    int end = (d + 1 < n) ? offs[d + 1] : e_cnt;
    float dvd = dinv[d];
    float acc = 0.0f;
    for (int k = start; k < end; ++k) {
        int s = esrc[k];
        float w = dinv[s] * dvd;
        acc += w * proj[(size_t)s * DC + j];
    }
    float* o = (j < DOUT) ? (out + (size_t)d * DOUT + j)
                          : (out + (size_t)n * DOUT + (size_t)d * DOUT + (j - DOUT));
    *o += acc;  // exclusive owner, non-atomic RMW
}

// ======================= fallback (round-1 atomic) path =======================

__global__ void k_init_deg(float* __restrict__ deg, int n) {
    int i = blockIdx.x * blockDim.x + threadIdx.x;
    if (i < n) deg[i] = 1.0f;
}

__global__ void k_count(const int* __restrict__ dst, float* __restrict__ deg, int e_cnt) {
    int e = blockIdx.x * blockDim.x + threadIdx.x;
    if (e < e_cnt) unsafeAtomicAdd(&deg[dst[e]], 1.0f);
}

__global__ void k_projF(const float* __restrict__ x,
                        const float* __restrict__ Wmu, const float* __restrict__ bmu,
                        const float* __restrict__ Wls, const float* __restrict__ bls,
                        float* __restrict__ deg_dinv, float* __restrict__ proj,
                        float* __restrict__ out, int n) {
    __shared__ float Ws[DIN * DC];
    __shared__ float bs[DC];
    int t = threadIdx.x;
    for (int idx = t; idx < DIN * DC; idx += blockDim.x) {
        int k = idx >> 5, j = idx & 31;
        Ws[idx] = (j < DOUT) ? Wmu[k * DOUT + j] : Wls[k * DOUT + (j - DOUT)];
    }
    if (t < DC) bs[t] = (t < DOUT) ? bmu[t] : bls[t - DOUT];
    __syncthreads();
    int i = blockIdx.x * blockDim.x + t;
    if (i >= n) return;
    float xr[DIN];
    const float4* xp = reinterpret_cast<const float4*>(x + (size_t)i * DIN);
#pragma unroll
    for (int q = 0; q < DIN / 4; ++q) {
        float4 v = xp[q];
        xr[4 * q + 0] = v.x; xr[4 * q + 1] = v.y;
        xr[4 * q + 2] = v.z; xr[4 * q + 3] = v.w;
    }
    float acc[DC];
#pragma unroll
    for (int j = 0; j < DC; ++j) acc[j] = 0.0f;
#pragma unroll 4
    for (int k = 0; k < DIN; ++k) {
        float xv = xr[k];
#pragma unroll
        for (int j = 0; j < DC; ++j) acc[j] += xv * Ws[k * DC + j];
    }
    float dv = rsqrtf(deg_dinv[i]);
    deg_dinv[i] = dv;
    float d2 = dv * dv;
    float4* pp = reinterpret_cast<float4*>(proj + (size_t)i * DC);
#pragma unroll
    for (int q = 0; q < DC / 4; ++q) {
        float4 v;
        v.x = acc[4 * q + 0]; v.y = acc[4 * q + 1];
        v.z = acc[4 * q + 2]; v.w = acc[4 * q + 3];
        pp[q] = v;
    }
    float* omu = out + (size_t)i * DOUT;
    float* ols = out + (size_t)n * DOUT + (size_t)i * DOUT;
#pragma unroll
    for (int j = 0; j < DOUT; ++j) omu[j] = bs[j] + d2 * acc[j];
#pragma unroll
    for (int j = 0; j < DOUT; ++j) ols[j] = bs[DOUT + j] + d2 * acc[DOUT + j];
}

__global__ void k_scatterF(const int* __restrict__ src, const int* __restrict__ dst,
                           const float* __restrict__ dinv, const float* __restrict__ proj,
                           float* __restrict__ out, int e_cnt, int n) {
    long long gid = (long long)blockIdx.x * blockDim.x + threadIdx.x;
    int e = (int)(gid >> 5);
    int j = (int)(gid & 31);
    if (e >= e_cnt) return;
    int s = src[e], d = dst[e];
    float norm = dinv[s] * dinv[d];
    float v = norm * proj[(size_t)s * DC + j];
    float* o = (j < DOUT) ? (out + (size_t)d * DOUT + j)
                          : (out + (size_t)n * DOUT + (size_t)d * DOUT + (j - DOUT));
    unsafeAtomicAdd(o, v);
}

// ======================= launch =======================

extern "C" void kernel_launch(void* const* d_in, const int* in_sizes, int n_in,
                              void* d_out, int out_size, void* d_ws, size_t ws_size,
                              hipStream_t stream) {
    const float* x   = (const float*)d_in[0];
    const int*   ei  = (const int*)d_in[1];
    const float* Wmu = (const float*)d_in[2];
    const float* bmu = (const float*)d_in[3];
    const float* Wls = (const float*)d_in[4];
    const float* bls = (const float*)d_in[5];
    float* out = (float*)d_out;

    int n = in_sizes[0] / DIN;       // 100000
    int e_cnt = in_sizes[1] / 2;     // 1600000
    const int* src = ei;
    const int* dst = ei + e_cnt;

    int nb = (n + 255) / 256;        // scan blocks (must be <=512)

    size_t need = (size_t)4 * n * 4      /* cnt, fill, offs, dinv */
                + 512 * 4                /* bsum */
                + (size_t)n * DC * 4     /* proj */
                + (size_t)e_cnt * 4;     /* esrc */

    if (nb <= 512 && ws_size >= need) {
        char* w = (char*)d_ws;
        int*   cnt  = (int*)w;               w += (size_t)n * 4;
        int*   fill = (int*)w;               w += (size_t)n * 4;
        int*   offs = (int*)w;               w += (size_t)n * 4;
        int*   bsum = (int*)w;               w += 512 * 4;
        float* dinv = (float*)w;             w += (size_t)n * 4;
        float* proj = (float*)w;             w += (size_t)n * DC * 4;
        int*   esrc = (int*)w;

        int nblk = (n + 255) / 256;
        int eblk = (e_cnt + 255) / 256;
        k_init_i<<<nblk, 256, 0, stream>>>(cnt, fill, n);
        k_hist<<<eblk, 256, 0, stream>>>(dst, cnt, e_cnt);
        k_proj2<<<nblk, 256, 0, stream>>>(x, Wmu, bmu, Wls, bls, cnt, dinv, proj, out, n);
        k_scanA<<<nb, 256, 0, stream>>>(cnt, offs, bsum, n);
        k_scanB<<<1, 512, 0, stream>>>(bsum, nb);
        k_scanC<<<nblk, 256, 0, stream>>>(offs, bsum, n);
        k_reorder<<<eblk, 256, 0, stream>>>(src, dst, offs, fill, esrc, e_cnt);
        k_agg<<<(n + 7) / 8, 256, 0, stream>>>(esrc, offs, dinv, proj, out, n, e_cnt);
    } else {
        float* deg  = (float*)d_ws;
        float* proj = deg + n;
        k_init_deg<<<(n + 255) / 256, 256, 0, stream>>>(deg, n);
        k_count<<<(e_cnt + 255) / 256, 256, 0, stream>>>(dst, deg, e_cnt);
        k_projF<<<(n + 255) / 256, 256, 0, stream>>>(x, Wmu, bmu, Wls, bls, deg, proj, out, n);
        long long tasks = (long long)e_cnt * DC;
        k_scatterF<<<(int)((tasks + 255) / 256), 256, 0, stream>>>(src, dst, deg, proj, out, e_cnt, n);
    }
}